// Round 1
// 524.305 us; speedup vs baseline: 1.0515x; 1.0515x over previous
//
#include <hip/hip_runtime.h>
#include <stdint.h>

// Problem constants (B=2, Nr=40962, in_ch=128, out_ch=64). FP32 I/O.
#define NR     40962
#define NH     163842      // 4*NR-6
#define NR7    286734      // NR*7
#define M_UP   40962
#define M_CV   327684      // B*NH
#define BN_EPS 1e-5f
#define SLOPE  0.2f

typedef __attribute__((ext_vector_type(8))) short  short8;
typedef __attribute__((ext_vector_type(4))) short  s16x4;
typedef __attribute__((ext_vector_type(4))) float  f32x4;
typedef unsigned short ushort_t;

__device__ __forceinline__ ushort_t f2bf(float f) {
  union { float f; uint32_t u; } v; v.f = f;
  uint32_t r = v.u + 0x7fffu + ((v.u >> 16) & 1u);  // RNE
  return (ushort_t)(r >> 16);
}
__device__ __forceinline__ float bf2f(ushort_t h) {
  union { uint32_t u; float f; } v; v.u = ((uint32_t)h) << 16;
  return v.f;
}
__device__ __forceinline__ int clampi(int v, int hi) {
  v = v < 0 ? 0 : v;
  return v >= hi ? hi - 1 : v;
}

// Async global->LDS, 16B per lane. LDS dest must be waveBase + lane*16.
__device__ __forceinline__ void gload_lds16(const void* g, void* l) {
  __builtin_amdgcn_global_load_lds(
      (__attribute__((address_space(1))) void*)(void*)g,
      (__attribute__((address_space(3))) void*)l, 16, 0, 0);
}

// ---------------------------------------------------------------------------
// MFMA gather-GEMM, 128x64 tile, BK=64, double-buffered LDS, bf16 compute.
// MODE 0: dense A bf16 [M][128] (up-GEMM, K=128), out bf16.
// MODE 1: conv1 gather: k -> (j=k>>7, c=k&127), A row = xcat[gb*NH+idx][128],
//         out bf16.
// MODE 2: conv2 gather: k -> (j=k>>6, c=k&63), A row = y1[gb*NH+idx][64],
//         out fp32.
// W is read fp32 [K][N] directly (no Wt buffer: during conv1 only ~91KB of
// slack exists across d_out+ws; fp32 W comes free from d_in, L2-hot).
// A staged via global_load_lds (linear LDS dest, inverse-swizzled source);
// LDS rows = 64 elems (128B), slot swizzle: slot ^= (row&7) -> ~2-way banks.
// Pipeline per chunk: loadB(t+1) -> stageA_gll(t+1) -> MFMA(t) -> writeB(t+1)
// -> barrier (drains gll).  One barrier per chunk.
// FSTATS: fused per-channel sum/sumsq -> statsPart[16 slices][128].
// ---------------------------------------------------------------------------
template<int MODE, bool FSTATS>
__global__ __launch_bounds__(256) void gemm_mfma(
    const ushort_t* __restrict__ Asrc,
    const int*      __restrict__ neigh,
    const float*    __restrict__ Wf,     // fp32 [K][N]
    const float*    __restrict__ bias,
    void*           __restrict__ OutV,
    float*          __restrict__ statsPart,
    int M, int N, int K)
{
  __shared__ __align__(16) ushort_t As[2][128 * 64];
  __shared__ __align__(16) ushort_t Bs[2][64 * 64];
  __shared__ int Ns[1024];   // [row][8] full gathered row index (gb*NH+idx)

  const int tid  = threadIdx.x;
  const int wv   = tid >> 6;
  const int lane = tid & 63;
  const int r16  = lane & 15;
  const int q    = lane >> 4;
  const int mTile = blockIdx.y * 128;
  const int nTile = blockIdx.x * 64;

  if constexpr (MODE != 0) {
    for (int i = tid; i < 1024; i += 256) {
      const int rr = i >> 3, jj = i & 7;
      if (jj < 7) {
        int a_m = mTile + rr; if (a_m >= M) a_m = M - 1;
        const int gb = (a_m >= NH) ? 1 : 0;
        const int gn = a_m - gb * NH;
        Ns[i] = gb * NH + clampi(neigh[gn * 7 + jj], NH);
      }
    }
  }

  f32x4 acc[2][4];
#pragma unroll
  for (int a = 0; a < 2; ++a)
#pragma unroll
    for (int i = 0; i < 4; ++i) acc[a][i] = (f32x4){0.f, 0.f, 0.f, 0.f};

  const int arL = lane >> 3;     // row within 8-row group
  const int psl = lane & 7;      // physical 16B slot
  const int bnq = tid & 15;      // B: n-quad
  const int bkq = tid >> 4;      // B: k-quad 0..15

  // A stage: per wave 4 issues x 64 lanes x 16B = 4KB (rows [32wv,32wv+32)).
  auto stageA = [&](int buf, int ch) {
    const int k0 = ch << 6;
    const int slot = psl ^ arL;  // logical slot held at physical psl
#pragma unroll
    for (int i = 0; i < 4; ++i) {
      const int r = wv * 32 + i * 8 + arL;   // r&7 == arL
      size_t srcOff;
      if constexpr (MODE == 0) {
        int a_m = mTile + r; if (a_m >= M) a_m = M - 1;
        srcOff = (size_t)a_m * 128 + k0 + slot * 8;
      } else if constexpr (MODE == 1) {
        srcOff = (size_t)Ns[r * 8 + (k0 >> 7)] * 128 + (k0 & 127) + slot * 8;
      } else {
        srcOff = (size_t)Ns[r * 8 + (k0 >> 6)] * 64 + slot * 8;
      }
      gload_lds16(Asrc + srcOff, &As[buf][r * 64 + psl * 8]);
    }
  };

  // B: thread covers 4n x 4k; coalesced float4 rows of W.
  auto loadB = [&](f32x4* f, int ch) {
    const int kk = (ch << 6) + bkq * 4;
#pragma unroll
    for (int e = 0; e < 4; ++e)
      f[e] = *(const f32x4*)(Wf + (size_t)(kk + e) * N + nTile + bnq * 4);
  };
  auto writeB = [&](int buf, f32x4* f) {
    const int s = bkq >> 1, h = bkq & 1;
#pragma unroll
    for (int d = 0; d < 4; ++d) {
      const int n  = bnq * 4 + d;
      const int sp = s ^ (n & 7);
      s16x4 v;
      v[0] = (short)f2bf(f[0][d]); v[1] = (short)f2bf(f[1][d]);
      v[2] = (short)f2bf(f[2][d]); v[3] = (short)f2bf(f[3][d]);
      *(s16x4*)&Bs[buf][n * 64 + sp * 8 + h * 4] = v;
    }
  };

  auto compute = [&](int buf) {
#pragma unroll
    for (int ks = 0; ks < 2; ++ks) {
      const int s = (ks * 4 + q) ^ (r16 & 7);
      const short8 a0 = *(const short8*)&As[buf][(wv * 32 + r16) * 64 + s * 8];
      const short8 a1 = *(const short8*)&As[buf][(wv * 32 + 16 + r16) * 64 + s * 8];
#pragma unroll
      for (int ct = 0; ct < 4; ++ct) {
        const short8 b = *(const short8*)&Bs[buf][(ct * 16 + r16) * 64 + s * 8];
        acc[0][ct] = __builtin_amdgcn_mfma_f32_16x16x32_bf16(a0, b, acc[0][ct], 0, 0, 0);
        acc[1][ct] = __builtin_amdgcn_mfma_f32_16x16x32_bf16(a1, b, acc[1][ct], 0, 0, 0);
      }
    }
  };

  const int nCh = K >> 6;
  if constexpr (MODE != 0) __syncthreads();   // Ns visible to stageA
  {
    f32x4 f[4];
    loadB(f, 0);         // issue B first so writeB's wait leaves gll in flight
    stageA(0, 0);
    writeB(0, f);
  }
  __syncthreads();

  int buf = 0;
  for (int ch = 0; ch < nCh; ++ch) {
    f32x4 f[4];
    const bool pf = (ch + 1 < nCh);
    if (pf) { loadB(f, ch + 1); stageA(buf ^ 1, ch + 1); }
    compute(buf);
    if (pf) writeB(buf ^ 1, f);
    __syncthreads();     // drains gll + ds_writes; releases buf for reuse
    buf ^= 1;
  }

  // epilogue: C/D layout col=lane&15, row=(lane>>4)*4+reg
  float s[4]  = {0.f, 0.f, 0.f, 0.f};
  float s2[4] = {0.f, 0.f, 0.f, 0.f};
#pragma unroll
  for (int ct = 0; ct < 4; ++ct) {
    const int colg = nTile + ct * 16 + r16;
    const float bv = bias[colg];
#pragma unroll
    for (int af = 0; af < 2; ++af) {
#pragma unroll
      for (int i = 0; i < 4; ++i) {
        const int rowg = mTile + wv * 32 + af * 16 + q * 4 + i;
        const float y = acc[af][ct][i] + bv;
        if (rowg < M) {
          if constexpr (MODE == 2)
            ((float*)OutV)[(size_t)rowg * N + colg] = y;
          else
            ((ushort_t*)OutV)[(size_t)rowg * N + colg] = f2bf(y);
          if constexpr (FSTATS) { s[ct] += y; s2[ct] += y * y; }
        }
      }
    }
  }

  if constexpr (FSTATS) {
    __syncthreads();                     // all LDS use done; reuse As
    float* Sred  = (float*)&As[0][0];    // [4 waves][64 ch]
    float* S2red = Sred + 256;
#pragma unroll
    for (int ct = 0; ct < 4; ++ct) {
      float v = s[ct], w = s2[ct];
      v += __shfl_xor(v, 16, 64); v += __shfl_xor(v, 32, 64);
      w += __shfl_xor(w, 16, 64); w += __shfl_xor(w, 32, 64);
      if (q == 0) {
        Sred[wv * 64 + ct * 16 + r16]  = v;
        S2red[wv * 64 + ct * 16 + r16] = w;
      }
    }
    __syncthreads();
    if (tid < 64) {
      float v = Sred[tid] + Sred[64 + tid] + Sred[128 + tid] + Sred[192 + tid];
      float w = S2red[tid] + S2red[64 + tid] + S2red[128 + tid] + S2red[192 + tid];
      float* p = statsPart + (size_t)(blockIdx.y & 15) * 128;
      atomicAdd(&p[tid], v);
      atomicAdd(&p[64 + tid], w);
    }
  }
}

// ---------------------------------------------------------------------------
// xup build: pick/mean from h ((NR,448) bf16 viewed as (NR7,64)), writing the
// LOW 64 channels of xcat rows (row stride 128).
// ---------------------------------------------------------------------------
__global__ __launch_bounds__(256) void build_xup_kernel(
    const ushort_t* __restrict__ h, const int* __restrict__ top,
    const int* __restrict__ down, ushort_t* __restrict__ xcatB, long long total)
{
  const long long gid = (long long)blockIdx.x * 256 + threadIdx.x;
  if (gid >= total) return;
  const int n  = (int)(gid >> 3);
  const int c0 = (int)(gid & 7) * 8;
  short8 v;
  if (n < NR) {
    const int idx = clampi(top[n], NR7);
    v = *(const short8*)(h + (size_t)idx * 64 + c0);
  } else {
    const int d  = n - NR;
    const int i0 = clampi(down[d * 2], NR7);
    const int i1 = clampi(down[d * 2 + 1], NR7);
    short8 u0 = *(const short8*)(h + (size_t)i0 * 64 + c0);
    short8 u1 = *(const short8*)(h + (size_t)i1 * 64 + c0);
#pragma unroll
    for (int i = 0; i < 8; ++i)
      v[i] = (short)f2bf(0.5f * (bf2f((ushort_t)u0[i]) + bf2f((ushort_t)u1[i])));
  }
  *(short8*)(xcatB + (size_t)n * 128 + c0) = v;
}

// x2 fp32 -> bf16 into HIGH 64 channels of xcat (row stride 128)
__global__ __launch_bounds__(256) void cvt_x2_kernel(
    const float* __restrict__ x2, ushort_t* __restrict__ xcat, long long n8)
{
  const long long gid = (long long)blockIdx.x * 256 + threadIdx.x;
  if (gid >= n8) return;
  const long long n = gid >> 3;
  const int c0 = (int)(gid & 7) * 8;
  const f32x4 f0 = *(const f32x4*)(x2 + n * 64 + c0);
  const f32x4 f1 = *(const f32x4*)(x2 + n * 64 + c0 + 4);
  short8 v;
#pragma unroll
  for (int i = 0; i < 4; ++i) {
    v[i]     = (short)f2bf(f0[i]);
    v[i + 4] = (short)f2bf(f1[i]);
  }
  *(short8*)(xcat + n * 128 + 64 + c0) = v;
}

// x1 fp32 -> bf16 dense [40962][128]
__global__ __launch_bounds__(256) void cvt_bf_kernel(
    const float* __restrict__ src, ushort_t* __restrict__ dst, long long n8)
{
  const long long gid = (long long)blockIdx.x * 256 + threadIdx.x;
  if (gid >= n8) return;
  const f32x4 f0 = *(const f32x4*)(src + gid * 8);
  const f32x4 f1 = *(const f32x4*)(src + gid * 8 + 4);
  short8 v;
#pragma unroll
  for (int i = 0; i < 4; ++i) {
    v[i]     = (short)f2bf(f0[i]);
    v[i + 4] = (short)f2bf(f1[i]);
  }
  *(short8*)(dst + gid * 8) = v;
}

__global__ __launch_bounds__(256) void zero_kernel(float* __restrict__ p, int n) {
  const int gid = blockIdx.x * 256 + threadIdx.x;
  if (gid < n) p[gid] = 0.f;
}

// Fallback stats over fp32 buffer -> 16 partial slices
__global__ __launch_bounds__(256) void stats_f32_kernel(
    const float* __restrict__ buf, float* __restrict__ part, int rows)
{
  const int tid = threadIdx.x;
  const int c   = tid & 63;
  const int rl  = tid >> 6;
  float s = 0.f, s2 = 0.f;
  for (int r = blockIdx.x * 4 + rl; r < rows; r += gridDim.x * 4) {
    const float v = buf[(size_t)r * 64 + c];
    s += v; s2 += v * v;
  }
  __shared__ float sh[2][256];
  sh[0][tid] = s; sh[1][tid] = s2;
  __syncthreads();
  if (tid < 64) {
#pragma unroll
    for (int i = 1; i < 4; ++i) { s += sh[0][tid + 64 * i]; s2 += sh[1][tid + 64 * i]; }
    float* p = part + (size_t)(blockIdx.x & 15) * 128;
    atomicAdd(&p[c], s);
    atomicAdd(&p[64 + c], s2);
  }
}

// Fallback stats over bf16 buffer -> 16 partial slices
__global__ __launch_bounds__(256) void stats_bf16_kernel(
    const ushort_t* __restrict__ buf, float* __restrict__ part, int rows)
{
  const int tid = threadIdx.x;
  const int c   = tid & 63;
  const int rl  = tid >> 6;
  float s = 0.f, s2 = 0.f;
  for (int r = blockIdx.x * 4 + rl; r < rows; r += gridDim.x * 4) {
    const float v = bf2f(buf[(size_t)r * 64 + c]);
    s += v; s2 += v * v;
  }
  __shared__ float sh[2][256];
  sh[0][tid] = s; sh[1][tid] = s2;
  __syncthreads();
  if (tid < 64) {
#pragma unroll
    for (int i = 1; i < 4; ++i) { s += sh[0][tid + 64 * i]; s2 += sh[1][tid + 64 * i]; }
    float* p = part + (size_t)(blockIdx.x & 15) * 128;
    atomicAdd(&p[c], s);
    atomicAdd(&p[64 + c], s2);
  }
}

// Reduce 16 partial slices -> final [sc[64] | sh[64]] at part+2048
__global__ void finalize_kernel(float* __restrict__ part,
                                const float* __restrict__ gamma,
                                const float* __restrict__ beta)
{
  const int c = threadIdx.x;  // 64
  float s = 0.f, s2 = 0.f;
  for (int i = 0; i < 16; ++i) { s += part[i * 128 + c]; s2 += part[i * 128 + 64 + c]; }
  const float invN = 1.0f / (float)M_CV;
  const float mean = s * invN;
  float var = fmaxf(s2 * invN - mean * mean, 0.f);
  const float sc = gamma[c] * rsqrtf(var + BN_EPS);
  float* fin = part + 2048;
  fin[c] = sc;
  fin[64 + c] = beta[c] - mean * sc;
}

// In-place y = lrelu(v*sc[c] + sh[c]); fin = [sc[64] | sh[64]]
template<bool F32>
__global__ __launch_bounds__(256) void bnl_kernel(
    void* __restrict__ bufV, const float* __restrict__ fin, long long nvec)
{
  const long long gid = (long long)blockIdx.x * 256 + threadIdx.x;
  if (gid >= nvec) return;
  if constexpr (F32) {
    float* buf = (float*)bufV;
    const int c0 = (int)((gid * 4) & 63);
    f32x4 v = *(f32x4*)(buf + gid * 4);
#pragma unroll
    for (int i = 0; i < 4; ++i) {
      const float y = v[i] * fin[c0 + i] + fin[64 + c0 + i];
      v[i] = (y >= 0.f) ? y : SLOPE * y;
    }
    *(f32x4*)(buf + gid * 4) = v;
  } else {
    ushort_t* buf = (ushort_t*)bufV;
    const int c0 = (int)((gid * 8) & 63);
    short8 v = *(short8*)(buf + gid * 8);
#pragma unroll
    for (int i = 0; i < 8; ++i) {
      float y = bf2f((ushort_t)v[i]) * fin[c0 + i] + fin[64 + c0 + i];
      y = (y >= 0.f) ? y : SLOPE * y;
      v[i] = (short)f2bf(y);
    }
    *(short8*)(buf + gid * 8) = v;
  }
}

// ---------------------------------------------------------------------------
extern "C" void kernel_launch(void* const* d_in, const int* in_sizes, int n_in,
                              void* d_out, int out_size, void* d_ws, size_t ws_size,
                              hipStream_t stream)
{
  const float* x1   = (const float*)d_in[0];
  const float* x2   = (const float*)d_in[1];
  const int*   neigh= (const int*)d_in[2];
  const int*   top  = (const int*)d_in[3];
  const int*   down = (const int*)d_in[4];
  const float* upW  = (const float*)d_in[5];
  const float* upb  = (const float*)d_in[6];
  const float* c1W  = (const float*)d_in[7];
  const float* c1b  = (const float*)d_in[8];
  const float* g1   = (const float*)d_in[9];
  const float* b1   = (const float*)d_in[10];
  const float* c2W  = (const float*)d_in[11];
  const float* c2b  = (const float*)d_in[12];
  const float* g2   = (const float*)d_in[13];
  const float* b2   = (const float*)d_in[14];

  // d_out (83,887,104 B) staging plan:
  //   [0, 83886080)  xcat bf16 [B*NH][128]: cols 0:64 = xup, 64:128 = bf16(x2)
  //   x1bf (10,486,272 B) overlays the start of batch-b's xcat region; it is
  //   dead before build_xup/cvt_x2 write there (strictly sequential stream).
  //   xcat dead after conv1 -> out fp32 reuses d_out.
  // ws: y1 bf16 [B*NH][64] = 41,943,552 (h bf16 36.7MB overlays it in phase 1).
  //   Gated tail (+17,408 B): st1 (8,704) + st2 (8,704), each
  //   16 slices x 128 floats + 128 final.
  // All weights are read fp32 directly from d_in inside the GEMMs (during
  // conv1 the live set xcat+y1 leaves only ~91KB slack -> no room for Wt).
  char* dob = (char*)d_out;
  ushort_t* xcat = (ushort_t*)dob;
  float*    outb = (float*)d_out;
  ushort_t* hbuf = (ushort_t*)d_ws;
  ushort_t* ybuf = (ushort_t*)d_ws;

  const bool gated = ws_size >= (size_t)(41943552 + 17408);
  float* st1 = gated ? (float*)((char*)d_ws + 41943552) : (float*)d_out;
  float* st2 = gated ? (float*)((char*)d_ws + 41943552 + 8704) : (float*)d_ws;

  if (gated) zero_kernel<<<17, 256, 0, stream>>>(st1, 4352);  // st1+st2 adjacent

  // Phase 1 — per batch: x1->bf16 (overlay); h = x1bf @ upW + upb; xup->xcat
  for (int b = 0; b < 2; ++b) {
    ushort_t* x1bf = xcat + (size_t)b * NH * 128;
    cvt_bf_kernel<<<2561, 256, 0, stream>>>(x1 + (size_t)b * M_UP * 128,
                                            x1bf, 655392LL);
    gemm_mfma<0, false><<<dim3(7, 321), 256, 0, stream>>>(
        x1bf, nullptr, upW, upb, hbuf, nullptr, M_UP, 448, 128);
    build_xup_kernel<<<5121, 256, 0, stream>>>(
        hbuf, top, down, xcat + (size_t)b * NH * 128, (long long)NH * 8);
  }
  // x2 -> bf16 high channels (after both up-GEMMs: overwrites x1bf overlays)
  cvt_x2_kernel<<<10241, 256, 0, stream>>>(x2, xcat, 2621472LL);

  // Phase 2 — y1 = meshconv1(xcat) -> ws (+ fused BN1 stats if gated)
  if (gated) {
    gemm_mfma<1, true><<<dim3(1, 2561), 256, 0, stream>>>(
        xcat, neigh, c1W, c1b, ybuf, st1, M_CV, 64, 896);
  } else {
    gemm_mfma<1, false><<<dim3(1, 2561), 256, 0, stream>>>(
        xcat, neigh, c1W, c1b, ybuf, nullptr, M_CV, 64, 896);
    zero_kernel<<<9, 256, 0, stream>>>(st1, 2176);     // xcat dead now
    stats_bf16_kernel<<<2048, 256, 0, stream>>>(ybuf, st1, M_CV);
  }
  finalize_kernel<<<1, 64, 0, stream>>>(st1, g1, b1);
  bnl_kernel<false><<<10241, 256, 0, stream>>>(ybuf, st1 + 2048, 2621472LL);

  // Phase 3 — out = meshconv2(y1) -> d_out fp32 (+ fused BN2 stats if gated)
  if (gated) {
    gemm_mfma<2, true><<<dim3(1, 2561), 256, 0, stream>>>(
        ybuf, neigh, c2W, c2b, outb, st2, M_CV, 64, 448);
  } else {
    gemm_mfma<2, false><<<dim3(1, 2561), 256, 0, stream>>>(
        ybuf, neigh, c2W, c2b, outb, nullptr, M_CV, 64, 448);
    zero_kernel<<<9, 256, 0, stream>>>(st2, 2176);     // y1 dead now
    stats_f32_kernel<<<2048, 256, 0, stream>>>(outb, st2, M_CV);
  }
  finalize_kernel<<<1, 64, 0, stream>>>(st2, g2, b2);
  bnl_kernel<true><<<20481, 256, 0, stream>>>(outb, st2 + 2048, 5242944LL);
}